// Round 2
// baseline (412.866 us; speedup 1.0000x reference)
//
#include <hip/hip_runtime.h>

// Conv2d: input (64,8,256,256) f32, filter (8,8,3,3) OIHW, VALID, stride 1.
// out (64,8,254,254) f32.
//
// No input LDS: reuse (3x in y, 1.5x in x) is captured by L1/L2/L3 (round-1
// FETCH_SIZE=100MB < compulsory 134MB proved caches dedupe). Thread = 4
// consecutive x-pixels at one (n,y), all 8 output channels -> 32 accumulators.
// Filter repacked once into 2.3KB LDS [c][r][m][s] so each (c,r) step is 6
// broadcast ds_read_b128. Occupancy-bound by VGPR only.

__global__ __launch_bounds__(256, 6)
void conv2d_direct_kernel(const float* __restrict__ inp,
                          const float* __restrict__ filt,
                          float* __restrict__ out) {
    __shared__ float s_f[576];   // [c][r][m][s] : ((c*3+r)*8+m)*3+s

    const int tid = threadIdx.x;
    // stage + repack filter (OIHW -> c,r,m,s)
    for (int i = tid; i < 576; i += 256) {
        int m = i / 72;
        int c = (i / 9) % 8;
        int r = (i / 3) % 3;
        int s = i % 3;
        s_f[((c * 3 + r) * 8 + m) * 3 + s] = filt[i];
    }
    __syncthreads();

    const int xb = tid & 63;         // 64 x-blocks of 4 -> x 0..255
    const int yy = tid >> 6;         // 4 rows per block
    const int yg = blockIdx.x;       // 64 y-groups
    const int n  = blockIdx.y;       // 64 batches
    const int y  = yg * 4 + yy;
    if (y >= 254) return;            // only after the single barrier
    const int x0 = xb * 4;

    const float* in_n = inp + (size_t)n * (8 * 256 * 256);

    float acc[8][4];
    #pragma unroll
    for (int m = 0; m < 8; ++m)
        #pragma unroll
        for (int i = 0; i < 4; ++i) acc[m][i] = 0.0f;

    // tail x-block: float2 at +2 instead of +4 (stays in-bounds; iv[4],iv[5]
    // then only feed px>=254 accs which are never stored)
    const int o2 = (x0 <= 250) ? 4 : 2;

    for (int c = 0; c < 8; ++c) {
        const float* ip = in_n + ((c * 256 + y) * 256 + x0);
        #pragma unroll
        for (int r = 0; r < 3; ++r) {
            float iv[6];
            const float4 v0 = *(const float4*)(ip + r * 256);       // 16B aligned
            iv[0] = v0.x; iv[1] = v0.y; iv[2] = v0.z; iv[3] = v0.w;
            const float2 v1 = *(const float2*)(ip + r * 256 + o2);  // 8B aligned
            iv[4] = v1.x; iv[5] = v1.y;

            float fr[24];
            const float* fp = &s_f[(c * 3 + r) * 24];
            #pragma unroll
            for (int j = 0; j < 24; ++j) fr[j] = fp[j];             // 6x ds_read_b128, broadcast

            #pragma unroll
            for (int s = 0; s < 3; ++s) {
                #pragma unroll
                for (int m = 0; m < 8; ++m) {
                    const float fv = fr[m * 3 + s];
                    #pragma unroll
                    for (int i = 0; i < 4; ++i)
                        acc[m][i] = fmaf(iv[i + s], fv, acc[m][i]);
                }
            }
        }
    }

    // store: 8 m x 4 px as float2 pairs (row offset always even -> 8B aligned)
    const bool full = (x0 + 4 <= 254);
    #pragma unroll
    for (int m = 0; m < 8; ++m) {
        float* op = out + ((((size_t)n * 8 + m) * 254 + y) * 254 + x0);
        float2 lo; lo.x = acc[m][0]; lo.y = acc[m][1];
        *(float2*)op = lo;
        if (full) {
            float2 hi; hi.x = acc[m][2]; hi.y = acc[m][3];
            *(float2*)(op + 2) = hi;
        }
    }
}

extern "C" void kernel_launch(void* const* d_in, const int* in_sizes, int n_in,
                              void* d_out, int out_size, void* d_ws, size_t ws_size,
                              hipStream_t stream) {
    const float* inp  = (const float*)d_in[0];   // (64,8,256,256)
    const float* filt = (const float*)d_in[1];   // (8,8,3,3)
    float* outp = (float*)d_out;                 // (64,8,254,254)

    dim3 grid(64, 64);   // (y-groups of 4, n)
    dim3 block(256);
    conv2d_direct_kernel<<<grid, block, 0, stream>>>(inp, filt, outp);
}